// Round 4
// baseline (2731.883 us; speedup 1.0000x reference)
//
#include <hip/hip_runtime.h>

#define NTOK  32768
#define NE    8192
#define DIM   256
#define EPSF  8.0e-4f
#define CAP   31

typedef __attribute__((ext_vector_type(8))) short short8;
typedef __attribute__((ext_vector_type(4))) float f32x4;

static __device__ __forceinline__ unsigned pk32(float f) {
  unsigned u = __float_as_uint(f);
  return (u & 0x80000000u) ? ~u : (u | 0x80000000u);
}
static __device__ __forceinline__ float upk32(unsigned p) {
  unsigned u = (p & 0x80000000u) ? (p & 0x7fffffffu) : ~p;
  return __uint_as_float(u);
}
static __device__ __forceinline__ unsigned long long pk64(float s, int idx) {
  return ((unsigned long long)pk32(s) << 32) | (unsigned)idx;
}
static __device__ __forceinline__ unsigned short bf16rne(float f) {
  unsigned u = __float_as_uint(f);
  unsigned r = u + 0x7fffu + ((u >> 16) & 1u);
  return (unsigned short)(r >> 16);
}
static __device__ __forceinline__ void gld16(const void* g, void* l) {
  __builtin_amdgcn_global_load_lds(
      (const __attribute__((address_space(1))) unsigned int*)g,
      (__attribute__((address_space(3))) unsigned int*)l, 16, 0, 0);
}

// ---------------- K1: prep (z2/e2 numpy-pairwise exact, bf16 copies, inits) --
__global__ __launch_bounds__(256) void vq_prep(const float* __restrict__ z,
                                               const float* __restrict__ emb,
                                               float* __restrict__ e2,
                                               float* __restrict__ z2,
                                               unsigned* __restrict__ gmin,
                                               unsigned* __restrict__ list,
                                               unsigned short* __restrict__ zb,
                                               unsigned short* __restrict__ eb,
                                               float* __restrict__ loss_slot) {
  int gid = blockIdx.x * 256 + threadIdx.x;
  if (gid < NTOK) { gmin[gid] = 0xFFFFFFFFu; list[(size_t)gid * 32] = 0u; }
  if (gid == 0) loss_slot[0] = 0.0f;

  int wave = gid >> 6;
  int lane = threadIdx.x & 63;
  int row = wave * 16 + (lane >> 2);            // 0..40959
  int sub = lane & 3;
  int q = sub & 1, h = sub >> 1;

  const float* src = (row < NTOK) ? (z + (size_t)row * DIM)
                                  : (emb + (size_t)(row - NTOK) * DIM);
  unsigned short* dst = (row < NTOK) ? (zb + (size_t)row * DIM)
                                     : (eb + (size_t)(row - NTOK) * DIM);
  const float4* p = reinterpret_cast<const float4*>(src + h * 128 + q * 4);

  float r0, r1, r2, r3, s;
  {
    #pragma clang fp contract(off)
    r0 = 0.0f; r1 = 0.0f; r2 = 0.0f; r3 = 0.0f;
    #pragma unroll
    for (int t = 0; t < 16; t++) {
      float4 v = p[2 * t];
      // bf16 copy of this strip
      ushort4 w;
      w.x = bf16rne(v.x); w.y = bf16rne(v.y); w.z = bf16rne(v.z); w.w = bf16rne(v.w);
      *reinterpret_cast<ushort4*>(dst + h * 128 + q * 4 + t * 8) = w;
      float q0 = v.x * v.x, q1 = v.y * v.y, q2 = v.z * v.z, q3 = v.w * v.w;
      r0 = r0 + q0; r1 = r1 + q1; r2 = r2 + q2; r3 = r3 + q3;
    }
    s = (r0 + r1) + (r2 + r3);
    s = s + __shfl_xor(s, 1, 64);
    s = s + __shfl_xor(s, 2, 64);
  }
  if (sub == 0) {
    if (row < NTOK) z2[row] = s;
    else            e2[row - NTOK] = s;
  }
}

// ---------------- K2: bf16 MFMA scoring + candidate collection ---------------
__global__ __launch_bounds__(256, 2) void vq_mfma(const unsigned short* __restrict__ zb,
                                                  const unsigned short* __restrict__ eb,
                                                  const float* __restrict__ e2,
                                                  unsigned* __restrict__ gmin,
                                                  unsigned* __restrict__ list) {
  __shared__ unsigned short Ab[128 * 32];
  __shared__ unsigned short Bb[128 * 32];
  __shared__ unsigned lmin[128];
  __shared__ float thrF[128];

  const int tid = threadIdx.x;
  const int t0 = blockIdx.x * 128;
  const int e0 = blockIdx.y * 128;
  if (tid < 128) lmin[tid] = 0xFFFFFFFFu;
  const int lane = tid & 63;
  const int wv = tid >> 6;
  const int wm = wv & 1, wn = wv >> 1;

  f32x4 acc[4][4];
  #pragma unroll
  for (int i = 0; i < 4; i++)
    #pragma unroll
    for (int j = 0; j < 4; j++) acc[i][j] = (f32x4)0.0f;

  // staging: rows (tid>>2) in 64-row chunks, 16B k-strips (tid&3)
  const size_t gra = (size_t)(t0 + (tid >> 2)) * DIM + (tid & 3) * 8;
  const size_t grb = (size_t)(e0 + (tid >> 2)) * DIM + (tid & 3) * 8;
  char* la0 = (char*)Ab + tid * 16;
  char* lb0 = (char*)Bb + tid * 16;

  const int arix = (wm * 64 + (lane & 15)) * 32 + (lane >> 4) * 8;
  const int brix = (wn * 64 + (lane & 15)) * 32 + (lane >> 4) * 8;

  for (int kc = 0; kc < DIM; kc += 32) {
    __syncthreads();
    gld16(zb + gra + kc, la0);
    gld16(zb + gra + (size_t)64 * DIM + kc, la0 + 4096);
    gld16(eb + grb + kc, lb0);
    gld16(eb + grb + (size_t)64 * DIM + kc, lb0 + 4096);
    __syncthreads();
    short8 a[4], b[4];
    #pragma unroll
    for (int f = 0; f < 4; f++) {
      a[f] = *reinterpret_cast<const short8*>(&Ab[arix + f * 16 * 32]);
      b[f] = *reinterpret_cast<const short8*>(&Bb[brix + f * 16 * 32]);
    }
    #pragma unroll
    for (int fi = 0; fi < 4; fi++)
      #pragma unroll
      for (int fj = 0; fj < 4; fj++)
        acc[fi][fj] = __builtin_amdgcn_mfma_f32_16x16x32_bf16(a[fi], b[fj], acc[fi][fj], 0, 0, 0);
  }

  // epilogue: s'' = e2[c] - 2*dot ; pass 1: block-local per-token min
  float e2c[4];
  #pragma unroll
  for (int fj = 0; fj < 4; fj++)
    e2c[fj] = e2[e0 + wn * 64 + fj * 16 + (lane & 15)];

  #pragma unroll
  for (int fi = 0; fi < 4; fi++) {
    #pragma unroll
    for (int r = 0; r < 4; r++) {
      int tl = wm * 64 + fi * 16 + ((lane >> 4) << 2) + r;
      float mn = 1.0e30f;
      #pragma unroll
      for (int fj = 0; fj < 4; fj++) {
        float s = fmaf(-2.0f, acc[fi][fj][r], e2c[fj]);
        mn = fminf(mn, s);
      }
      atomicMin(&lmin[tl], pk32(mn));
    }
  }
  __syncthreads();
  if (tid < 128) {
    unsigned lm = lmin[tid];
    unsigned old = atomicMin(&gmin[t0 + tid], lm);
    unsigned m = old < lm ? old : lm;
    thrF[tid] = upk32(m) + EPSF;
  }
  __syncthreads();
  // pass 2: push candidates within threshold (superset of ref-argmin achievers)
  #pragma unroll
  for (int fi = 0; fi < 4; fi++) {
    #pragma unroll
    for (int r = 0; r < 4; r++) {
      int tl = wm * 64 + fi * 16 + ((lane >> 4) << 2) + r;
      float th = thrF[tl];
      #pragma unroll
      for (int fj = 0; fj < 4; fj++) {
        float s = fmaf(-2.0f, acc[fi][fj][r], e2c[fj]);
        if (s <= th) {
          unsigned* L = list + (size_t)(t0 + tl) * 32;
          unsigned pos = atomicAdd(L, 1u);
          if (pos < CAP) L[1 + pos] = (unsigned)(e0 + wn * 64 + fj * 16 + (lane & 15));
        }
      }
    }
  }
}

// exact reference-semantics score: m = fma-chain(2z_k * e_k), s = (z2-m)+e2
static __device__ __forceinline__ float exact_score(const float* __restrict__ zr,
                                                    const float* __restrict__ er,
                                                    float z2t, float e2c) {
  float m = 0.0f;
  {
    #pragma clang fp contract(off)
    #pragma unroll 8
    for (int k = 0; k < DIM; k++) m = fmaf(2.0f * zr[k], er[k], m);
    float t1 = z2t - m;
    float s = t1 + e2c;
    return s;
  }
}

// ---------------- K3: exact rescore of candidates + outputs ------------------
__global__ __launch_bounds__(256) void vq_resolve(const float* __restrict__ z,
                                                  const float* __restrict__ emb,
                                                  const float* __restrict__ z2,
                                                  const float* __restrict__ e2,
                                                  const unsigned* __restrict__ list,
                                                  float* __restrict__ out_zq,
                                                  float* __restrict__ out_loss,
                                                  float* __restrict__ out_idx) {
  const int lane = threadIdx.x & 63;
  const int wv = threadIdx.x >> 6;
  const int t = blockIdx.x * 4 + wv;
  const unsigned* L = list + (size_t)t * 32;
  unsigned craw = L[0];
  if (craw > CAP) return;                        // overflow -> K4 handles
  int winner;
  if (craw == 1) {
    winner = (int)L[1];
  } else {
    unsigned long long best = ~0ull;
    if (lane < (int)craw) {
      int c = (int)L[1 + lane];
      float s = exact_score(z + (size_t)t * DIM, emb + (size_t)c * DIM, z2[t], e2[c]);
      best = pk64(s, c);
    }
    #pragma unroll
    for (int off = 32; off > 0; off >>= 1) {
      unsigned long long o = __shfl_xor(best, off, 64);
      best = o < best ? o : best;
    }
    winner = (int)(best & 0xffffffffu);
  }
  const float4 zz = reinterpret_cast<const float4*>(z + (size_t)t * DIM)[lane];
  const float4 ee = reinterpret_cast<const float4*>(emb + (size_t)winner * DIM)[lane];
  reinterpret_cast<float4*>(out_zq + (size_t)t * DIM)[lane] = ee;
  float dx = ee.x - zz.x, dy = ee.y - zz.y, dz = ee.z - zz.z, dw = ee.w - zz.w;
  float d = dx * dx + dy * dy + dz * dz + dw * dw;
  #pragma unroll
  for (int off = 32; off > 0; off >>= 1) d += __shfl_down(d, off, 64);
  if (lane == 0) {
    atomicAdd(out_loss, d * (1.25f / 8388608.0f));
    out_idx[t] = (float)winner;
  }
}

// ---------------- K4: brute-force fallback for overflowed tokens -------------
__global__ __launch_bounds__(256) void vq_brute(const float* __restrict__ z,
                                                const float* __restrict__ emb,
                                                const float* __restrict__ z2,
                                                const float* __restrict__ e2,
                                                const unsigned* __restrict__ list,
                                                float* __restrict__ out_zq,
                                                float* __restrict__ out_loss,
                                                float* __restrict__ out_idx) {
  const int lane = threadIdx.x & 63;
  const int wv = threadIdx.x >> 6;
  const int t = blockIdx.x * 4 + wv;
  if (list[(size_t)t * 32] <= CAP) return;
  unsigned long long best = ~0ull;
  const float* zr = z + (size_t)t * DIM;
  for (int cb = 0; cb < NE / 64; cb++) {
    int c = cb * 64 + lane;
    float s = exact_score(zr, emb + (size_t)c * DIM, z2[t], e2[c]);
    unsigned long long kk = pk64(s, c);
    best = kk < best ? kk : best;
  }
  #pragma unroll
  for (int off = 32; off > 0; off >>= 1) {
    unsigned long long o = __shfl_xor(best, off, 64);
    best = o < best ? o : best;
  }
  int winner = (int)(best & 0xffffffffu);
  const float4 zz = reinterpret_cast<const float4*>(zr)[lane];
  const float4 ee = reinterpret_cast<const float4*>(emb + (size_t)winner * DIM)[lane];
  reinterpret_cast<float4*>(out_zq + (size_t)t * DIM)[lane] = ee;
  float dx = ee.x - zz.x, dy = ee.y - zz.y, dz = ee.z - zz.z, dw = ee.w - zz.w;
  float d = dx * dx + dy * dy + dz * dz + dw * dw;
  #pragma unroll
  for (int off = 32; off > 0; off >>= 1) d += __shfl_down(d, off, 64);
  if (lane == 0) {
    atomicAdd(out_loss, d * (1.25f / 8388608.0f));
    out_idx[t] = (float)winner;
  }
}

// ====================== round-3 verified fallback path =======================
#define BT 128
#define BE 128
#define BK 32
#define LDW 132

__global__ __launch_bounds__(256) void fb_init(const float* __restrict__ z,
                                               const float* __restrict__ emb,
                                               float* __restrict__ e2,
                                               float* __restrict__ z2,
                                               unsigned long long* __restrict__ k1,
                                               float* __restrict__ loss_slot) {
  int gid = blockIdx.x * 256 + threadIdx.x;
  if (gid < NTOK) k1[gid] = ~0ull;
  if (gid == 0) loss_slot[0] = 0.0f;
  int wave = gid >> 6;
  int lane = threadIdx.x & 63;
  int row = wave * 16 + (lane >> 2);
  int sub = lane & 3;
  int q = sub & 1, h = sub >> 1;
  const float* src = (row < NTOK) ? (z + (size_t)row * DIM)
                                  : (emb + (size_t)(row - NTOK) * DIM);
  const float4* p = reinterpret_cast<const float4*>(src + h * 128 + q * 4);
  float r0, r1, r2, r3, s;
  {
    #pragma clang fp contract(off)
    r0 = 0.0f; r1 = 0.0f; r2 = 0.0f; r3 = 0.0f;
    #pragma unroll
    for (int t = 0; t < 16; t++) {
      float4 v = p[2 * t];
      float q0 = v.x * v.x, q1 = v.y * v.y, q2 = v.z * v.z, q3 = v.w * v.w;
      r0 = r0 + q0; r1 = r1 + q1; r2 = r2 + q2; r3 = r3 + q3;
    }
    s = (r0 + r1) + (r2 + r3);
    s = s + __shfl_xor(s, 1, 64);
    s = s + __shfl_xor(s, 2, 64);
  }
  if (sub == 0) {
    if (row < NTOK) z2[row] = s;
    else            e2[row - NTOK] = s;
  }
}

__global__ __launch_bounds__(256, 4) void fb_score(const float* __restrict__ z,
                                                   const float* __restrict__ emb,
                                                   const float* __restrict__ e2,
                                                   const float* __restrict__ z2,
                                                   unsigned long long* __restrict__ k1) {
  __shared__ float As[BK][LDW];
  __shared__ float Bs[BK][LDW];
  __shared__ unsigned long long mkey[BT];
  const int tid = threadIdx.x;
  const int t0 = blockIdx.x * BT;
  const int e0 = blockIdx.y * BE;
  const int tx = tid & 15;
  const int ty = tid >> 4;
  if (tid < BT) mkey[tid] = ~0ull;
  float acc[8][8];
  #pragma unroll
  for (int i = 0; i < 8; i++)
    #pragma unroll
    for (int j = 0; j < 8; j++) acc[i][j] = 0.0f;
  const float* __restrict__ zt = z + (size_t)t0 * DIM;
  const float* __restrict__ et = emb + (size_t)e0 * DIM;
  for (int kc = 0; kc < DIM; kc += BK) {
    __syncthreads();
    #pragma unroll
    for (int i = 0; i < 4; i++) {
      int f = tid + i * 256;
      int row = f >> 3;
      int kq = f & 7;
      const float4 va = *reinterpret_cast<const float4*>(zt + row * DIM + kc + kq * 4);
      const float4 vb = *reinterpret_cast<const float4*>(et + row * DIM + kc + kq * 4);
      int k = kq * 4;
      As[k + 0][row] = va.x * 2.0f; As[k + 1][row] = va.y * 2.0f;
      As[k + 2][row] = va.z * 2.0f; As[k + 3][row] = va.w * 2.0f;
      Bs[k + 0][row] = vb.x; Bs[k + 1][row] = vb.y;
      Bs[k + 2][row] = vb.z; Bs[k + 3][row] = vb.w;
    }
    __syncthreads();
    #pragma unroll 4
    for (int k = 0; k < BK; k++) {
      float a[8], b[8];
      *(float4*)&a[0] = *(const float4*)&As[k][ty * 8];
      *(float4*)&a[4] = *(const float4*)&As[k][ty * 8 + 4];
      *(float4*)&b[0] = *(const float4*)&Bs[k][tx * 8];
      *(float4*)&b[4] = *(const float4*)&Bs[k][tx * 8 + 4];
      #pragma unroll
      for (int i = 0; i < 8; i++)
        #pragma unroll
        for (int j = 0; j < 8; j++)
          acc[i][j] = fmaf(a[i], b[j], acc[i][j]);
    }
  }
  float e2c[8], z2t[8];
  *(float4*)&e2c[0] = *(const float4*)(e2 + e0 + tx * 8);
  *(float4*)&e2c[4] = *(const float4*)(e2 + e0 + tx * 8 + 4);
  *(float4*)&z2t[0] = *(const float4*)(z2 + t0 + ty * 8);
  *(float4*)&z2t[4] = *(const float4*)(z2 + t0 + ty * 8 + 4);
  {
    #pragma clang fp contract(off)
    #pragma unroll
    for (int i = 0; i < 8; i++) {
      int trow = ty * 8 + i;
      unsigned long long best = ~0ull;
      #pragma unroll
      for (int j = 0; j < 8; j++) {
        float t1 = z2t[i] - acc[i][j];
        float s = t1 + e2c[j];
        unsigned long long kk = pk64(s, e0 + tx * 8 + j);
        best = kk < best ? kk : best;
      }
      atomicMin(&mkey[trow], best);
    }
  }
  __syncthreads();
  if (tid < BT) atomicMin(&k1[t0 + tid], mkey[tid]);
}

__global__ __launch_bounds__(256) void fb_out(const float* __restrict__ z,
                                              const float* __restrict__ emb,
                                              const unsigned long long* __restrict__ k1,
                                              float* __restrict__ out_zq,
                                              float* __restrict__ out_loss,
                                              float* __restrict__ out_idx) {
  __shared__ float lsum[4];
  const int wid = threadIdx.x >> 6;
  const int lane = threadIdx.x & 63;
  const int tbase = blockIdx.x * 16 + wid * 4;
  float s_acc = 0.0f;
  #pragma unroll
  for (int it = 0; it < 4; it++) {
    int t = tbase + it;
    unsigned idx = (unsigned)(k1[t] & 0xffffffffu);
    float4 e = reinterpret_cast<const float4*>(emb + (size_t)idx * DIM)[lane];
    float4 zz = reinterpret_cast<const float4*>(z + (size_t)t * DIM)[lane];
    reinterpret_cast<float4*>(out_zq + (size_t)t * DIM)[lane] = e;
    float dx = e.x - zz.x, dy = e.y - zz.y, dz = e.z - zz.z, dw = e.w - zz.w;
    s_acc += dx * dx + dy * dy + dz * dz + dw * dw;
    if (lane == 0) out_idx[t] = (float)idx;
  }
  #pragma unroll
  for (int off = 32; off > 0; off >>= 1) s_acc += __shfl_down(s_acc, off, 64);
  if (lane == 0) lsum[wid] = s_acc;
  __syncthreads();
  if (threadIdx.x == 0) {
    float tot = (lsum[0] + lsum[1] + lsum[2] + lsum[3]) * (1.25f / 8388608.0f);
    atomicAdd(out_loss, tot);
  }
}

// ============================== launcher =====================================
extern "C" void kernel_launch(void* const* d_in, const int* in_sizes, int n_in,
                              void* d_out, int out_size, void* d_ws, size_t ws_size,
                              hipStream_t stream) {
  const float* z = (const float*)d_in[0];
  const float* emb = (const float*)d_in[1];
  float* out = (float*)d_out;
  float* out_zq = out;
  float* out_loss = out + (size_t)NTOK * DIM;
  float* out_idx = out_loss + 1;

  // ws offsets (fast path): e2 | z2 | gmin | list | zb | eb
  const size_t OFF_Z2 = 32768;
  const size_t OFF_GMIN = 163840;
  const size_t OFF_LIST = 294912;
  const size_t OFF_ZB = 4489216;
  const size_t OFF_EB = 21266432;
  const size_t REQ = 25460736;

  if (ws_size >= REQ) {
    float* e2 = (float*)d_ws;
    float* z2 = (float*)((char*)d_ws + OFF_Z2);
    unsigned* gmin = (unsigned*)((char*)d_ws + OFF_GMIN);
    unsigned* list = (unsigned*)((char*)d_ws + OFF_LIST);
    unsigned short* zb = (unsigned short*)((char*)d_ws + OFF_ZB);
    unsigned short* eb = (unsigned short*)((char*)d_ws + OFF_EB);

    hipLaunchKernelGGL(vq_prep, dim3(640), dim3(256), 0, stream,
                       z, emb, e2, z2, gmin, list, zb, eb, out_loss);
    hipLaunchKernelGGL(vq_mfma, dim3(NTOK / 128, NE / 128), dim3(256), 0, stream,
                       zb, eb, e2, gmin, list);
    hipLaunchKernelGGL(vq_resolve, dim3(NTOK / 4), dim3(256), 0, stream,
                       z, emb, z2, e2, list, out_zq, out_loss, out_idx);
    hipLaunchKernelGGL(vq_brute, dim3(NTOK / 4), dim3(256), 0, stream,
                       z, emb, z2, e2, list, out_zq, out_loss, out_idx);
  } else {
    float* e2 = (float*)d_ws;
    float* z2 = (float*)((char*)d_ws + 32768);
    unsigned long long* k1 = (unsigned long long*)((char*)d_ws + 262144);
    hipLaunchKernelGGL(fb_init, dim3(640), dim3(256), 0, stream,
                       z, emb, e2, z2, k1, out_loss);
    hipLaunchKernelGGL(fb_score, dim3(NTOK / BT, NE / BE), dim3(256), 0, stream,
                       z, emb, e2, z2, k1);
    hipLaunchKernelGGL(fb_out, dim3(NTOK / 16), dim3(256), 0, stream,
                       z, emb, k1, out_zq, out_loss, out_idx);
  }
}

// Round 5
// 2717.877 us; speedup vs baseline: 1.0052x; 1.0052x over previous
//
#include <hip/hip_runtime.h>

#define NTOK  32768
#define NE    8192
#define DIM   256
#define EPSF  8.0e-4f

typedef __attribute__((ext_vector_type(8))) short short8;
typedef __attribute__((ext_vector_type(4))) float f32x4;

static __device__ __forceinline__ unsigned pk32(float f) {
  unsigned u = __float_as_uint(f);
  return (u & 0x80000000u) ? ~u : (u | 0x80000000u);
}
static __device__ __forceinline__ float upk32(unsigned p) {
  unsigned u = (p & 0x80000000u) ? (p & 0x7fffffffu) : ~p;
  return __uint_as_float(u);
}
static __device__ __forceinline__ unsigned long long pk64(float s, int idx) {
  return ((unsigned long long)pk32(s) << 32) | (unsigned)idx;
}
static __device__ __forceinline__ unsigned short bf16rne(float f) {
  unsigned u = __float_as_uint(f);
  unsigned r = u + 0x7fffu + ((u >> 16) & 1u);
  return (unsigned short)(r >> 16);
}
static __device__ __forceinline__ void gld16(const void* g, void* l) {
  __builtin_amdgcn_global_load_lds(
      (const __attribute__((address_space(1))) unsigned int*)g,
      (__attribute__((address_space(3))) unsigned int*)l, 16, 0, 0);
}

// ---------------- K1: prep (z2/e2 numpy-pairwise exact, bf16 copies) ---------
__global__ __launch_bounds__(256) void vq_prep(const float* __restrict__ z,
                                               const float* __restrict__ emb,
                                               float* __restrict__ e2,
                                               float* __restrict__ z2,
                                               unsigned short* __restrict__ zb,
                                               unsigned short* __restrict__ eb,
                                               float* __restrict__ loss_slot) {
  int gid = blockIdx.x * 256 + threadIdx.x;
  if (gid == 0) loss_slot[0] = 0.0f;

  int wave = gid >> 6;
  int lane = threadIdx.x & 63;
  int row = wave * 16 + (lane >> 2);            // 0..40959
  int sub = lane & 3;
  int q = sub & 1, h = sub >> 1;

  const float* src = (row < NTOK) ? (z + (size_t)row * DIM)
                                  : (emb + (size_t)(row - NTOK) * DIM);
  unsigned short* dst = (row < NTOK) ? (zb + (size_t)row * DIM)
                                     : (eb + (size_t)(row - NTOK) * DIM);
  const float4* p = reinterpret_cast<const float4*>(src + h * 128 + q * 4);

  float r0, r1, r2, r3, s;
  {
    #pragma clang fp contract(off)
    r0 = 0.0f; r1 = 0.0f; r2 = 0.0f; r3 = 0.0f;
    #pragma unroll
    for (int t = 0; t < 16; t++) {
      float4 v = p[2 * t];
      ushort4 w;
      w.x = bf16rne(v.x); w.y = bf16rne(v.y); w.z = bf16rne(v.z); w.w = bf16rne(v.w);
      *reinterpret_cast<ushort4*>(dst + h * 128 + q * 4 + t * 8) = w;
      float q0 = v.x * v.x, q1 = v.y * v.y, q2 = v.z * v.z, q3 = v.w * v.w;
      r0 = r0 + q0; r1 = r1 + q1; r2 = r2 + q2; r3 = r3 + q3;
    }
    s = (r0 + r1) + (r2 + r3);
    s = s + __shfl_xor(s, 1, 64);
    s = s + __shfl_xor(s, 2, 64);
  }
  if (sub == 0) {
    if (row < NTOK) z2[row] = s;
    else            e2[row - NTOK] = s;
  }
}

// ---------------- K2: bf16 MFMA scoring -> per-(token, e-block) 16-bit min ---
__global__ __launch_bounds__(256, 2) void vq_mfma(const unsigned short* __restrict__ zb,
                                                  const unsigned short* __restrict__ eb,
                                                  const float* __restrict__ e2,
                                                  unsigned short* __restrict__ bmin) {
  __shared__ unsigned short Ab[128 * 32];
  __shared__ unsigned short Bb[128 * 32];
  __shared__ unsigned lmin[128];

  const int tid = threadIdx.x;
  const int t0 = blockIdx.x * 128;
  const int e0 = blockIdx.y * 128;
  if (tid < 128) lmin[tid] = 0xFFFFFFFFu;
  const int lane = tid & 63;
  const int wv = tid >> 6;
  const int wm = wv & 1, wn = wv >> 1;

  f32x4 acc[4][4];
  #pragma unroll
  for (int i = 0; i < 4; i++)
    #pragma unroll
    for (int j = 0; j < 4; j++) acc[i][j] = (f32x4)0.0f;

  const size_t gra = (size_t)(t0 + (tid >> 2)) * DIM + (tid & 3) * 8;
  const size_t grb = (size_t)(e0 + (tid >> 2)) * DIM + (tid & 3) * 8;
  char* la0 = (char*)Ab + tid * 16;
  char* lb0 = (char*)Bb + tid * 16;

  const int arix = (wm * 64 + (lane & 15)) * 32 + (lane >> 4) * 8;
  const int brix = (wn * 64 + (lane & 15)) * 32 + (lane >> 4) * 8;

  for (int kc = 0; kc < DIM; kc += 32) {
    __syncthreads();
    gld16(zb + gra + kc, la0);
    gld16(zb + gra + (size_t)64 * DIM + kc, la0 + 4096);
    gld16(eb + grb + kc, lb0);
    gld16(eb + grb + (size_t)64 * DIM + kc, lb0 + 4096);
    __syncthreads();
    short8 a[4], b[4];
    #pragma unroll
    for (int f = 0; f < 4; f++) {
      a[f] = *reinterpret_cast<const short8*>(&Ab[arix + f * 16 * 32]);
      b[f] = *reinterpret_cast<const short8*>(&Bb[brix + f * 16 * 32]);
    }
    #pragma unroll
    for (int fi = 0; fi < 4; fi++)
      #pragma unroll
      for (int fj = 0; fj < 4; fj++)
        acc[fi][fj] = __builtin_amdgcn_mfma_f32_16x16x32_bf16(a[fi], b[fj], acc[fi][fj], 0, 0, 0);
  }

  float e2c[4];
  #pragma unroll
  for (int fj = 0; fj < 4; fj++)
    e2c[fj] = e2[e0 + wn * 64 + fj * 16 + (lane & 15)];

  #pragma unroll
  for (int fi = 0; fi < 4; fi++) {
    #pragma unroll
    for (int r = 0; r < 4; r++) {
      int tl = wm * 64 + fi * 16 + ((lane >> 4) << 2) + r;
      float mn = 1.0e30f;
      #pragma unroll
      for (int fj = 0; fj < 4; fj++) {
        float s = fmaf(-2.0f, acc[fi][fj][r], e2c[fj]);
        mn = fminf(mn, s);
      }
      atomicMin(&lmin[tl], pk32(mn));
    }
  }
  __syncthreads();
  if (tid < 128)
    bmin[(size_t)(t0 + tid) * 64 + blockIdx.y] = (unsigned short)(lmin[tid] >> 16);
}

// ---------------- K3: flag blocks near min, exact fp32 rescore, outputs ------
__global__ __launch_bounds__(256) void vq_resolve(const float* __restrict__ z,
                                                  const float* __restrict__ emb,
                                                  const float* __restrict__ z2,
                                                  const float* __restrict__ e2,
                                                  const unsigned short* __restrict__ bmin,
                                                  float* __restrict__ out_zq,
                                                  float* __restrict__ out_loss,
                                                  float* __restrict__ out_idx) {
  __shared__ float zrow[4][256];
  __shared__ float lsum[4];
  const int lane = threadIdx.x & 63;
  const int wv = threadIdx.x >> 6;
  const int t = blockIdx.x * 4 + wv;

  // stage z row into LDS (per-wave, broadcast reads later)
  const float4 zz = reinterpret_cast<const float4*>(z + (size_t)t * DIM)[lane];
  *reinterpret_cast<float4*>(&zrow[wv][lane * 4]) = zz;

  // per-token min over 64 block minima (16-bit keys, lane y = lane)
  unsigned b16 = (unsigned)bmin[(size_t)t * 64 + lane];
  unsigned m16 = b16;
  #pragma unroll
  for (int off = 32; off > 0; off >>= 1) {
    unsigned o = __shfl_xor(m16, off, 64);
    m16 = o < m16 ? o : m16;
  }
  float m_hi = upk32((m16 << 16) | 0xFFFFu);    // upper bound on true global min
  float thr = m_hi + EPSF;
  float b_lo = upk32(b16 << 16);                // lower bound on this block's min
  unsigned long long mask = __ballot(b_lo <= thr);

  const float z2t = z2[t];
  unsigned long long best = ~0ull;
  while (mask) {
    int y = (int)__builtin_ctzll(mask);
    mask &= mask - 1;
    int c0 = y * 128 + lane;
    int c1 = c0 + 64;
    const float4* er0 = reinterpret_cast<const float4*>(emb + (size_t)c0 * DIM);
    const float4* er1 = reinterpret_cast<const float4*>(emb + (size_t)c1 * DIM);
    float m0, m1;
    {
      #pragma clang fp contract(off)
      m0 = 0.0f; m1 = 0.0f;
      #pragma unroll 8
      for (int k4 = 0; k4 < 64; k4++) {
        float4 zv = *reinterpret_cast<const float4*>(&zrow[wv][k4 * 4]);
        float4 e0v = er0[k4];
        float4 e1v = er1[k4];
        m0 = fmaf(2.0f * zv.x, e0v.x, m0); m1 = fmaf(2.0f * zv.x, e1v.x, m1);
        m0 = fmaf(2.0f * zv.y, e0v.y, m0); m1 = fmaf(2.0f * zv.y, e1v.y, m1);
        m0 = fmaf(2.0f * zv.z, e0v.z, m0); m1 = fmaf(2.0f * zv.z, e1v.z, m1);
        m0 = fmaf(2.0f * zv.w, e0v.w, m0); m1 = fmaf(2.0f * zv.w, e1v.w, m1);
      }
      float s0 = (z2t - m0) + e2[c0];
      float s1 = (z2t - m1) + e2[c1];
      unsigned long long k0 = pk64(s0, c0);
      unsigned long long k1 = pk64(s1, c1);
      best = k0 < best ? k0 : best;
      best = k1 < best ? k1 : best;
    }
  }
  #pragma unroll
  for (int off = 32; off > 0; off >>= 1) {
    unsigned long long o = __shfl_xor(best, off, 64);
    best = o < best ? o : best;
  }
  int winner = (int)(best & 0xffffffffu);

  const float4 ee = reinterpret_cast<const float4*>(emb + (size_t)winner * DIM)[lane];
  reinterpret_cast<float4*>(out_zq + (size_t)t * DIM)[lane] = ee;
  float dx = ee.x - zz.x, dy = ee.y - zz.y, dz = ee.z - zz.z, dw = ee.w - zz.w;
  float d = dx * dx + dy * dy + dz * dz + dw * dw;
  #pragma unroll
  for (int off = 32; off > 0; off >>= 1) d += __shfl_down(d, off, 64);
  if (lane == 0) {
    lsum[wv] = d;
    out_idx[t] = (float)winner;
  }
  __syncthreads();
  if (threadIdx.x == 0) {
    float tot = (lsum[0] + lsum[1] + lsum[2] + lsum[3]) * (1.25f / 8388608.0f);
    atomicAdd(out_loss, tot);
  }
}

// ====================== round-3 verified fallback path =======================
#define BT 128
#define BE 128
#define BK 32
#define LDW 132

__global__ __launch_bounds__(256) void fb_init(const float* __restrict__ z,
                                               const float* __restrict__ emb,
                                               float* __restrict__ e2,
                                               float* __restrict__ z2,
                                               unsigned long long* __restrict__ k1,
                                               float* __restrict__ loss_slot) {
  int gid = blockIdx.x * 256 + threadIdx.x;
  if (gid < NTOK) k1[gid] = ~0ull;
  if (gid == 0) loss_slot[0] = 0.0f;
  int wave = gid >> 6;
  int lane = threadIdx.x & 63;
  int row = wave * 16 + (lane >> 2);
  int sub = lane & 3;
  int q = sub & 1, h = sub >> 1;
  const float* src = (row < NTOK) ? (z + (size_t)row * DIM)
                                  : (emb + (size_t)(row - NTOK) * DIM);
  const float4* p = reinterpret_cast<const float4*>(src + h * 128 + q * 4);
  float r0, r1, r2, r3, s;
  {
    #pragma clang fp contract(off)
    r0 = 0.0f; r1 = 0.0f; r2 = 0.0f; r3 = 0.0f;
    #pragma unroll
    for (int t = 0; t < 16; t++) {
      float4 v = p[2 * t];
      float q0 = v.x * v.x, q1 = v.y * v.y, q2 = v.z * v.z, q3 = v.w * v.w;
      r0 = r0 + q0; r1 = r1 + q1; r2 = r2 + q2; r3 = r3 + q3;
    }
    s = (r0 + r1) + (r2 + r3);
    s = s + __shfl_xor(s, 1, 64);
    s = s + __shfl_xor(s, 2, 64);
  }
  if (sub == 0) {
    if (row < NTOK) z2[row] = s;
    else            e2[row - NTOK] = s;
  }
}

__global__ __launch_bounds__(256, 4) void fb_score(const float* __restrict__ z,
                                                   const float* __restrict__ emb,
                                                   const float* __restrict__ e2,
                                                   const float* __restrict__ z2,
                                                   unsigned long long* __restrict__ k1) {
  __shared__ float As[BK][LDW];
  __shared__ float Bs[BK][LDW];
  __shared__ unsigned long long mkey[BT];
  const int tid = threadIdx.x;
  const int t0 = blockIdx.x * BT;
  const int e0 = blockIdx.y * BE;
  const int tx = tid & 15;
  const int ty = tid >> 4;
  if (tid < BT) mkey[tid] = ~0ull;
  float acc[8][8];
  #pragma unroll
  for (int i = 0; i < 8; i++)
    #pragma unroll
    for (int j = 0; j < 8; j++) acc[i][j] = 0.0f;
  const float* __restrict__ zt = z + (size_t)t0 * DIM;
  const float* __restrict__ et = emb + (size_t)e0 * DIM;
  for (int kc = 0; kc < DIM; kc += BK) {
    __syncthreads();
    #pragma unroll
    for (int i = 0; i < 4; i++) {
      int f = tid + i * 256;
      int row = f >> 3;
      int kq = f & 7;
      const float4 va = *reinterpret_cast<const float4*>(zt + row * DIM + kc + kq * 4);
      const float4 vb = *reinterpret_cast<const float4*>(et + row * DIM + kc + kq * 4);
      int k = kq * 4;
      As[k + 0][row] = va.x * 2.0f; As[k + 1][row] = va.y * 2.0f;
      As[k + 2][row] = va.z * 2.0f; As[k + 3][row] = va.w * 2.0f;
      Bs[k + 0][row] = vb.x; Bs[k + 1][row] = vb.y;
      Bs[k + 2][row] = vb.z; Bs[k + 3][row] = vb.w;
    }
    __syncthreads();
    #pragma unroll 4
    for (int k = 0; k < BK; k++) {
      float a[8], b[8];
      *(float4*)&a[0] = *(const float4*)&As[k][ty * 8];
      *(float4*)&a[4] = *(const float4*)&As[k][ty * 8 + 4];
      *(float4*)&b[0] = *(const float4*)&Bs[k][tx * 8];
      *(float4*)&b[4] = *(const float4*)&Bs[k][tx * 8 + 4];
      #pragma unroll
      for (int i = 0; i < 8; i++)
        #pragma unroll
        for (int j = 0; j < 8; j++)
          acc[i][j] = fmaf(a[i], b[j], acc[i][j]);
    }
  }
  float e2c[8], z2t[8];
  *(float4*)&e2c[0] = *(const float4*)(e2 + e0 + tx * 8);
  *(float4*)&e2c[4] = *(const float4*)(e2 + e0 + tx * 8 + 4);
  *(float4*)&z2t[0] = *(const float4*)(z2 + t0 + ty * 8);
  *(float4*)&z2t[4] = *(const float4*)(z2 + t0 + ty * 8 + 4);
  {
    #pragma clang fp contract(off)
    #pragma unroll
    for (int i = 0; i < 8; i++) {
      int trow = ty * 8 + i;
      unsigned long long best = ~0ull;
      #pragma unroll
      for (int j = 0; j < 8; j++) {
        float t1 = z2t[i] - acc[i][j];
        float s = t1 + e2c[j];
        unsigned long long kk = pk64(s, e0 + tx * 8 + j);
        best = kk < best ? kk : best;
      }
      atomicMin(&mkey[trow], best);
    }
  }
  __syncthreads();
  if (tid < BT) atomicMin(&k1[t0 + tid], mkey[tid]);
}

__global__ __launch_bounds__(256) void fb_out(const float* __restrict__ z,
                                              const float* __restrict__ emb,
                                              const unsigned long long* __restrict__ k1,
                                              float* __restrict__ out_zq,
                                              float* __restrict__ out_loss,
                                              float* __restrict__ out_idx) {
  __shared__ float lsum[4];
  const int wid = threadIdx.x >> 6;
  const int lane = threadIdx.x & 63;
  const int tbase = blockIdx.x * 16 + wid * 4;
  float s_acc = 0.0f;
  #pragma unroll
  for (int it = 0; it < 4; it++) {
    int t = tbase + it;
    unsigned idx = (unsigned)(k1[t] & 0xffffffffu);
    float4 e = reinterpret_cast<const float4*>(emb + (size_t)idx * DIM)[lane];
    float4 zz = reinterpret_cast<const float4*>(z + (size_t)t * DIM)[lane];
    reinterpret_cast<float4*>(out_zq + (size_t)t * DIM)[lane] = e;
    float dx = e.x - zz.x, dy = e.y - zz.y, dz = e.z - zz.z, dw = e.w - zz.w;
    s_acc += dx * dx + dy * dy + dz * dz + dw * dw;
    if (lane == 0) out_idx[t] = (float)idx;
  }
  #pragma unroll
  for (int off = 32; off > 0; off >>= 1) s_acc += __shfl_down(s_acc, off, 64);
  if (lane == 0) lsum[wid] = s_acc;
  __syncthreads();
  if (threadIdx.x == 0) {
    float tot = (lsum[0] + lsum[1] + lsum[2] + lsum[3]) * (1.25f / 8388608.0f);
    atomicAdd(out_loss, tot);
  }
}

// ============================== launcher =====================================
extern "C" void kernel_launch(void* const* d_in, const int* in_sizes, int n_in,
                              void* d_out, int out_size, void* d_ws, size_t ws_size,
                              hipStream_t stream) {
  const float* z = (const float*)d_in[0];
  const float* emb = (const float*)d_in[1];
  float* out = (float*)d_out;
  float* out_zq = out;
  float* out_loss = out + (size_t)NTOK * DIM;
  float* out_idx = out_loss + 1;

  // ws offsets (fast path): e2 | z2 | bmin | zb | eb
  const size_t OFF_Z2   = 32768;
  const size_t OFF_BMIN = 163840;
  const size_t OFF_ZB   = 4358144;
  const size_t OFF_EB   = 21135360;
  const size_t REQ      = 25329664;

  if (ws_size >= REQ) {
    float* e2 = (float*)d_ws;
    float* z2 = (float*)((char*)d_ws + OFF_Z2);
    unsigned short* bmin = (unsigned short*)((char*)d_ws + OFF_BMIN);
    unsigned short* zb = (unsigned short*)((char*)d_ws + OFF_ZB);
    unsigned short* eb = (unsigned short*)((char*)d_ws + OFF_EB);

    hipLaunchKernelGGL(vq_prep, dim3(640), dim3(256), 0, stream,
                       z, emb, e2, z2, zb, eb, out_loss);
    hipLaunchKernelGGL(vq_mfma, dim3(NTOK / 128, NE / 128), dim3(256), 0, stream,
                       zb, eb, e2, bmin);
    hipLaunchKernelGGL(vq_resolve, dim3(NTOK / 4), dim3(256), 0, stream,
                       z, emb, z2, e2, bmin, out_zq, out_loss, out_idx);
  } else {
    float* e2 = (float*)d_ws;
    float* z2 = (float*)((char*)d_ws + 32768);
    unsigned long long* k1 = (unsigned long long*)((char*)d_ws + 262144);
    hipLaunchKernelGGL(fb_init, dim3(640), dim3(256), 0, stream,
                       z, emb, e2, z2, k1, out_loss);
    hipLaunchKernelGGL(fb_score, dim3(NTOK / BT, NE / BE), dim3(256), 0, stream,
                       z, emb, e2, z2, k1);
    hipLaunchKernelGGL(fb_out, dim3(NTOK / 16), dim3(256), 0, stream,
                       z, emb, k1, out_zq, out_loss, out_idx);
  }
}

// Round 6
// 1421.677 us; speedup vs baseline: 1.9216x; 1.9117x over previous
//
#include <hip/hip_runtime.h>

#define NTOK  32768
#define NE    8192
#define DIM   256
#define EPSF  8.0e-4f
#define LCAP  15

typedef __attribute__((ext_vector_type(8))) short short8;
typedef __attribute__((ext_vector_type(4))) float f32x4;

static __device__ __forceinline__ unsigned pk32(float f) {
  unsigned u = __float_as_uint(f);
  return (u & 0x80000000u) ? ~u : (u | 0x80000000u);
}
static __device__ __forceinline__ float upk32(unsigned p) {
  unsigned u = (p & 0x80000000u) ? (p & 0x7fffffffu) : ~p;
  return __uint_as_float(u);
}
static __device__ __forceinline__ unsigned long long pk64(float s, int idx) {
  return ((unsigned long long)pk32(s) << 32) | (unsigned)idx;
}
static __device__ __forceinline__ unsigned short bf16rne(float f) {
  unsigned u = __float_as_uint(f);
  unsigned r = u + 0x7fffu + ((u >> 16) & 1u);
  return (unsigned short)(r >> 16);
}
static __device__ __forceinline__ void gld16(const void* g, void* l) {
  __builtin_amdgcn_global_load_lds(
      (const __attribute__((address_space(1))) unsigned int*)g,
      (__attribute__((address_space(3))) unsigned int*)l, 16, 0, 0);
}

// ---------------- K1: prep (z2/e2 numpy-pairwise exact, bf16 copies, inits) --
__global__ __launch_bounds__(256) void vq_prep(const float* __restrict__ z,
                                               const float* __restrict__ emb,
                                               float* __restrict__ e2,
                                               float* __restrict__ z2,
                                               unsigned* __restrict__ gmin,
                                               unsigned* __restrict__ list,
                                               unsigned short* __restrict__ zb,
                                               unsigned short* __restrict__ eb,
                                               float* __restrict__ loss_slot) {
  int gid = blockIdx.x * 256 + threadIdx.x;
  if (gid < NTOK) { gmin[gid] = 0xFFFFFFFFu; list[(size_t)gid * 16] = 0u; }
  if (gid == 0) loss_slot[0] = 0.0f;

  int wave = gid >> 6;
  int lane = threadIdx.x & 63;
  int row = wave * 16 + (lane >> 2);            // 0..40959
  int sub = lane & 3;
  int q = sub & 1, h = sub >> 1;

  const float* src = (row < NTOK) ? (z + (size_t)row * DIM)
                                  : (emb + (size_t)(row - NTOK) * DIM);
  unsigned short* dst = (row < NTOK) ? (zb + (size_t)row * DIM)
                                     : (eb + (size_t)(row - NTOK) * DIM);
  const float4* p = reinterpret_cast<const float4*>(src + h * 128 + q * 4);

  float r0, r1, r2, r3, s;
  {
    #pragma clang fp contract(off)
    r0 = 0.0f; r1 = 0.0f; r2 = 0.0f; r3 = 0.0f;
    #pragma unroll
    for (int t = 0; t < 16; t++) {
      float4 v = p[2 * t];
      ushort4 w;
      w.x = bf16rne(v.x); w.y = bf16rne(v.y); w.z = bf16rne(v.z); w.w = bf16rne(v.w);
      *reinterpret_cast<ushort4*>(dst + h * 128 + q * 4 + t * 8) = w;
      float q0 = v.x * v.x, q1 = v.y * v.y, q2 = v.z * v.z, q3 = v.w * v.w;
      r0 = r0 + q0; r1 = r1 + q1; r2 = r2 + q2; r3 = r3 + q3;
    }
    s = (r0 + r1) + (r2 + r3);
    s = s + __shfl_xor(s, 1, 64);
    s = s + __shfl_xor(s, 2, 64);
  }
  if (sub == 0) {
    if (row < NTOK) z2[row] = s;
    else            e2[row - NTOK] = s;
  }
}

// ---------------- K2: bf16 MFMA scoring. collect=0: per-token global min.
//                  collect=1: identical GEMM, emit codes with s <= gmin+eps ---
__global__ __launch_bounds__(256, 2) void vq_mfma(const unsigned short* __restrict__ zb,
                                                  const unsigned short* __restrict__ eb,
                                                  const float* __restrict__ e2,
                                                  unsigned* __restrict__ gmin,
                                                  unsigned* __restrict__ list,
                                                  int collect) {
  __shared__ unsigned short Ab[128 * 32];
  __shared__ unsigned short Bb[128 * 32];
  __shared__ unsigned lmin[128];
  __shared__ float thrS[128];

  const int tid = threadIdx.x;
  const int t0 = blockIdx.x * 128;
  const int e0 = blockIdx.y * 128;
  if (tid < 128) lmin[tid] = 0xFFFFFFFFu;
  const int lane = tid & 63;
  const int wv = tid >> 6;
  const int wm = wv & 1, wn = wv >> 1;

  f32x4 acc[4][4];
  #pragma unroll
  for (int i = 0; i < 4; i++)
    #pragma unroll
    for (int j = 0; j < 4; j++) acc[i][j] = (f32x4)0.0f;

  const size_t gra = (size_t)(t0 + (tid >> 2)) * DIM + (tid & 3) * 8;
  const size_t grb = (size_t)(e0 + (tid >> 2)) * DIM + (tid & 3) * 8;
  char* la0 = (char*)Ab + tid * 16;
  char* lb0 = (char*)Bb + tid * 16;

  const int arix = (wm * 64 + (lane & 15)) * 32 + (lane >> 4) * 8;
  const int brix = (wn * 64 + (lane & 15)) * 32 + (lane >> 4) * 8;

  for (int kc = 0; kc < DIM; kc += 32) {
    __syncthreads();
    gld16(zb + gra + kc, la0);
    gld16(zb + gra + (size_t)64 * DIM + kc, la0 + 4096);
    gld16(eb + grb + kc, lb0);
    gld16(eb + grb + (size_t)64 * DIM + kc, lb0 + 4096);
    __syncthreads();
    short8 a[4], b[4];
    #pragma unroll
    for (int f = 0; f < 4; f++) {
      a[f] = *reinterpret_cast<const short8*>(&Ab[arix + f * 16 * 32]);
      b[f] = *reinterpret_cast<const short8*>(&Bb[brix + f * 16 * 32]);
    }
    #pragma unroll
    for (int fi = 0; fi < 4; fi++)
      #pragma unroll
      for (int fj = 0; fj < 4; fj++)
        acc[fi][fj] = __builtin_amdgcn_mfma_f32_16x16x32_bf16(a[fi], b[fj], acc[fi][fj], 0, 0, 0);
  }

  float e2c[4];
  #pragma unroll
  for (int fj = 0; fj < 4; fj++)
    e2c[fj] = e2[e0 + wn * 64 + fj * 16 + (lane & 15)];

  if (!collect) {
    // pass A: block-local per-token min -> global atomicMin (order-independent)
    #pragma unroll
    for (int fi = 0; fi < 4; fi++) {
      #pragma unroll
      for (int r = 0; r < 4; r++) {
        int tl = wm * 64 + fi * 16 + ((lane >> 4) << 2) + r;
        float mn = 1.0e30f;
        #pragma unroll
        for (int fj = 0; fj < 4; fj++) {
          float s = fmaf(-2.0f, acc[fi][fj][r], e2c[fj]);
          mn = fminf(mn, s);
        }
        atomicMin(&lmin[tl], pk32(mn));
      }
    }
    __syncthreads();
    if (tid < 128) atomicMin(&gmin[t0 + tid], lmin[tid]);
  } else {
    // pass B: deterministic threshold from final gmin; emit candidates
    __syncthreads();
    if (tid < 128) thrS[tid] = upk32(gmin[t0 + tid]) + EPSF;
    __syncthreads();
    #pragma unroll
    for (int fi = 0; fi < 4; fi++) {
      #pragma unroll
      for (int r = 0; r < 4; r++) {
        int tl = wm * 64 + fi * 16 + ((lane >> 4) << 2) + r;
        float th = thrS[tl];
        #pragma unroll
        for (int fj = 0; fj < 4; fj++) {
          float s = fmaf(-2.0f, acc[fi][fj][r], e2c[fj]);
          if (s <= th) {
            unsigned* L = list + (size_t)(t0 + tl) * 16;
            unsigned pos = atomicAdd(L, 1u);
            if (pos < LCAP) L[1 + pos] = (unsigned)(e0 + wn * 64 + fj * 16 + (lane & 15));
          }
        }
      }
    }
  }
}

// ---------------- K3: exact fp32 rescore of ~2 candidates/token + outputs ----
__global__ __launch_bounds__(256) void vq_resolve(const float* __restrict__ z,
                                                  const float* __restrict__ emb,
                                                  const float* __restrict__ z2,
                                                  const float* __restrict__ e2,
                                                  const unsigned* __restrict__ list,
                                                  float* __restrict__ out_zq,
                                                  float* __restrict__ out_loss,
                                                  float* __restrict__ out_idx) {
  __shared__ float zrow[4][256];
  __shared__ float lsum[4];
  const int lane = threadIdx.x & 63;
  const int wv = threadIdx.x >> 6;
  const int t = blockIdx.x * 4 + wv;

  const float4 zz = reinterpret_cast<const float4*>(z + (size_t)t * DIM)[lane];
  *reinterpret_cast<float4*>(&zrow[wv][lane * 4]) = zz;
  const float* zr = &zrow[wv][0];
  const float z2t = z2[t];

  const unsigned* L = list + (size_t)t * 16;
  unsigned cnt = L[0];
  int winner;

  if (cnt == 1) {
    winner = (int)L[1];
  } else if (cnt <= LCAP) {
    unsigned long long best = ~0ull;
    if (lane < (int)cnt) {
      int c = (int)L[1 + lane];
      const float* er = emb + (size_t)c * DIM;
      float m;
      {
        #pragma clang fp contract(off)
        m = 0.0f;
        #pragma unroll 8
        for (int k = 0; k < DIM; k++) m = fmaf(2.0f * zr[k], er[k], m);
        float s = (z2t - m) + e2[c];
        best = pk64(s, c);
      }
    }
    #pragma unroll
    for (int off = 32; off > 0; off >>= 1) {
      unsigned long long o = __shfl_xor(best, off, 64);
      best = o < best ? o : best;
    }
    winner = (int)(best & 0xffffffffu);
  } else {
    // overflow (statistically ~never): exact full scan
    unsigned long long best = ~0ull;
    for (int cb = 0; cb < NE / 64; cb++) {
      int c = cb * 64 + lane;
      const float* er = emb + (size_t)c * DIM;
      float m;
      {
        #pragma clang fp contract(off)
        m = 0.0f;
        #pragma unroll 8
        for (int k = 0; k < DIM; k++) m = fmaf(2.0f * zr[k], er[k], m);
        float s = (z2t - m) + e2[c];
        unsigned long long kk = pk64(s, c);
        best = kk < best ? kk : best;
      }
    }
    #pragma unroll
    for (int off = 32; off > 0; off >>= 1) {
      unsigned long long o = __shfl_xor(best, off, 64);
      best = o < best ? o : best;
    }
    winner = (int)(best & 0xffffffffu);
  }

  const float4 ee = reinterpret_cast<const float4*>(emb + (size_t)winner * DIM)[lane];
  reinterpret_cast<float4*>(out_zq + (size_t)t * DIM)[lane] = ee;
  float dx = ee.x - zz.x, dy = ee.y - zz.y, dz = ee.z - zz.z, dw = ee.w - zz.w;
  float d = dx * dx + dy * dy + dz * dz + dw * dw;
  #pragma unroll
  for (int off = 32; off > 0; off >>= 1) d += __shfl_down(d, off, 64);
  if (lane == 0) {
    lsum[wv] = d;
    out_idx[t] = (float)winner;
  }
  __syncthreads();
  if (threadIdx.x == 0) {
    float tot = (lsum[0] + lsum[1] + lsum[2] + lsum[3]) * (1.25f / 8388608.0f);
    atomicAdd(out_loss, tot);
  }
}

// ====================== round-3 verified fallback path =======================
#define BT 128
#define BE 128
#define BK 32
#define LDW 132

__global__ __launch_bounds__(256) void fb_init(const float* __restrict__ z,
                                               const float* __restrict__ emb,
                                               float* __restrict__ e2,
                                               float* __restrict__ z2,
                                               unsigned long long* __restrict__ k1,
                                               float* __restrict__ loss_slot) {
  int gid = blockIdx.x * 256 + threadIdx.x;
  if (gid < NTOK) k1[gid] = ~0ull;
  if (gid == 0) loss_slot[0] = 0.0f;
  int wave = gid >> 6;
  int lane = threadIdx.x & 63;
  int row = wave * 16 + (lane >> 2);
  int sub = lane & 3;
  int q = sub & 1, h = sub >> 1;
  const float* src = (row < NTOK) ? (z + (size_t)row * DIM)
                                  : (emb + (size_t)(row - NTOK) * DIM);
  const float4* p = reinterpret_cast<const float4*>(src + h * 128 + q * 4);
  float r0, r1, r2, r3, s;
  {
    #pragma clang fp contract(off)
    r0 = 0.0f; r1 = 0.0f; r2 = 0.0f; r3 = 0.0f;
    #pragma unroll
    for (int t = 0; t < 16; t++) {
      float4 v = p[2 * t];
      float q0 = v.x * v.x, q1 = v.y * v.y, q2 = v.z * v.z, q3 = v.w * v.w;
      r0 = r0 + q0; r1 = r1 + q1; r2 = r2 + q2; r3 = r3 + q3;
    }
    s = (r0 + r1) + (r2 + r3);
    s = s + __shfl_xor(s, 1, 64);
    s = s + __shfl_xor(s, 2, 64);
  }
  if (sub == 0) {
    if (row < NTOK) z2[row] = s;
    else            e2[row - NTOK] = s;
  }
}

__global__ __launch_bounds__(256, 4) void fb_score(const float* __restrict__ z,
                                                   const float* __restrict__ emb,
                                                   const float* __restrict__ e2,
                                                   const float* __restrict__ z2,
                                                   unsigned long long* __restrict__ k1) {
  __shared__ float As[BK][LDW];
  __shared__ float Bs[BK][LDW];
  __shared__ unsigned long long mkey[BT];
  const int tid = threadIdx.x;
  const int t0 = blockIdx.x * BT;
  const int e0 = blockIdx.y * BE;
  const int tx = tid & 15;
  const int ty = tid >> 4;
  if (tid < BT) mkey[tid] = ~0ull;
  float acc[8][8];
  #pragma unroll
  for (int i = 0; i < 8; i++)
    #pragma unroll
    for (int j = 0; j < 8; j++) acc[i][j] = 0.0f;
  const float* __restrict__ zt = z + (size_t)t0 * DIM;
  const float* __restrict__ et = emb + (size_t)e0 * DIM;
  for (int kc = 0; kc < DIM; kc += BK) {
    __syncthreads();
    #pragma unroll
    for (int i = 0; i < 4; i++) {
      int f = tid + i * 256;
      int row = f >> 3;
      int kq = f & 7;
      const float4 va = *reinterpret_cast<const float4*>(zt + row * DIM + kc + kq * 4);
      const float4 vb = *reinterpret_cast<const float4*>(et + row * DIM + kc + kq * 4);
      int k = kq * 4;
      As[k + 0][row] = va.x * 2.0f; As[k + 1][row] = va.y * 2.0f;
      As[k + 2][row] = va.z * 2.0f; As[k + 3][row] = va.w * 2.0f;
      Bs[k + 0][row] = vb.x; Bs[k + 1][row] = vb.y;
      Bs[k + 2][row] = vb.z; Bs[k + 3][row] = vb.w;
    }
    __syncthreads();
    #pragma unroll 4
    for (int k = 0; k < BK; k++) {
      float a[8], b[8];
      *(float4*)&a[0] = *(const float4*)&As[k][ty * 8];
      *(float4*)&a[4] = *(const float4*)&As[k][ty * 8 + 4];
      *(float4*)&b[0] = *(const float4*)&Bs[k][tx * 8];
      *(float4*)&b[4] = *(const float4*)&Bs[k][tx * 8 + 4];
      #pragma unroll
      for (int i = 0; i < 8; i++)
        #pragma unroll
        for (int j = 0; j < 8; j++)
          acc[i][j] = fmaf(a[i], b[j], acc[i][j]);
    }
  }
  float e2c[8], z2t[8];
  *(float4*)&e2c[0] = *(const float4*)(e2 + e0 + tx * 8);
  *(float4*)&e2c[4] = *(const float4*)(e2 + e0 + tx * 8 + 4);
  *(float4*)&z2t[0] = *(const float4*)(z2 + t0 + ty * 8);
  *(float4*)&z2t[4] = *(const float4*)(z2 + t0 + ty * 8 + 4);
  {
    #pragma clang fp contract(off)
    #pragma unroll
    for (int i = 0; i < 8; i++) {
      int trow = ty * 8 + i;
      unsigned long long best = ~0ull;
      #pragma unroll
      for (int j = 0; j < 8; j++) {
        float t1 = z2t[i] - acc[i][j];
        float s = t1 + e2c[j];
        unsigned long long kk = pk64(s, e0 + tx * 8 + j);
        best = kk < best ? kk : best;
      }
      atomicMin(&mkey[trow], best);
    }
  }
  __syncthreads();
  if (tid < BT) atomicMin(&k1[t0 + tid], mkey[tid]);
}

__global__ __launch_bounds__(256) void fb_out(const float* __restrict__ z,
                                              const float* __restrict__ emb,
                                              const unsigned long long* __restrict__ k1,
                                              float* __restrict__ out_zq,
                                              float* __restrict__ out_loss,
                                              float* __restrict__ out_idx) {
  __shared__ float lsum[4];
  const int wid = threadIdx.x >> 6;
  const int lane = threadIdx.x & 63;
  const int tbase = blockIdx.x * 16 + wid * 4;
  float s_acc = 0.0f;
  #pragma unroll
  for (int it = 0; it < 4; it++) {
    int t = tbase + it;
    unsigned idx = (unsigned)(k1[t] & 0xffffffffu);
    float4 e = reinterpret_cast<const float4*>(emb + (size_t)idx * DIM)[lane];
    float4 zz = reinterpret_cast<const float4*>(z + (size_t)t * DIM)[lane];
    reinterpret_cast<float4*>(out_zq + (size_t)t * DIM)[lane] = e;
    float dx = e.x - zz.x, dy = e.y - zz.y, dz = e.z - zz.z, dw = e.w - zz.w;
    s_acc += dx * dx + dy * dy + dz * dz + dw * dw;
    if (lane == 0) out_idx[t] = (float)idx;
  }
  #pragma unroll
  for (int off = 32; off > 0; off >>= 1) s_acc += __shfl_down(s_acc, off, 64);
  if (lane == 0) lsum[wid] = s_acc;
  __syncthreads();
  if (threadIdx.x == 0) {
    float tot = (lsum[0] + lsum[1] + lsum[2] + lsum[3]) * (1.25f / 8388608.0f);
    atomicAdd(out_loss, tot);
  }
}

// ============================== launcher =====================================
extern "C" void kernel_launch(void* const* d_in, const int* in_sizes, int n_in,
                              void* d_out, int out_size, void* d_ws, size_t ws_size,
                              hipStream_t stream) {
  const float* z = (const float*)d_in[0];
  const float* emb = (const float*)d_in[1];
  float* out = (float*)d_out;
  float* out_zq = out;
  float* out_loss = out + (size_t)NTOK * DIM;
  float* out_idx = out_loss + 1;

  // ws offsets (fast path): e2 | z2 | gmin | list | zb | eb
  const size_t OFF_Z2   = 32768;
  const size_t OFF_GMIN = 163840;
  const size_t OFF_LIST = 294912;
  const size_t OFF_ZB   = 2392064;
  const size_t OFF_EB   = 19169280;
  const size_t REQ      = 23363584;

  if (ws_size >= REQ) {
    float* e2 = (float*)d_ws;
    float* z2 = (float*)((char*)d_ws + OFF_Z2);
    unsigned* gmin = (unsigned*)((char*)d_ws + OFF_GMIN);
    unsigned* list = (unsigned*)((char*)d_ws + OFF_LIST);
    unsigned short* zb = (unsigned short*)((char*)d_ws + OFF_ZB);
    unsigned short* eb = (unsigned short*)((char*)d_ws + OFF_EB);

    hipLaunchKernelGGL(vq_prep, dim3(640), dim3(256), 0, stream,
                       z, emb, e2, z2, gmin, list, zb, eb, out_loss);
    hipLaunchKernelGGL(vq_mfma, dim3(NTOK / 128, NE / 128), dim3(256), 0, stream,
                       zb, eb, e2, gmin, list, 0);
    hipLaunchKernelGGL(vq_mfma, dim3(NTOK / 128, NE / 128), dim3(256), 0, stream,
                       zb, eb, e2, gmin, list, 1);
    hipLaunchKernelGGL(vq_resolve, dim3(NTOK / 4), dim3(256), 0, stream,
                       z, emb, z2, e2, list, out_zq, out_loss, out_idx);
  } else {
    float* e2 = (float*)d_ws;
    float* z2 = (float*)((char*)d_ws + 32768);
    unsigned long long* k1 = (unsigned long long*)((char*)d_ws + 262144);
    hipLaunchKernelGGL(fb_init, dim3(640), dim3(256), 0, stream,
                       z, emb, e2, z2, k1, out_loss);
    hipLaunchKernelGGL(fb_score, dim3(NTOK / BT, NE / BE), dim3(256), 0, stream,
                       z, emb, e2, z2, k1);
    hipLaunchKernelGGL(fb_out, dim3(NTOK / 16), dim3(256), 0, stream,
                       z, emb, k1, out_zq, out_loss, out_idx);
  }
}

// Round 7
// 1357.968 us; speedup vs baseline: 2.0117x; 1.0469x over previous
//
#include <hip/hip_runtime.h>

#define NTOK  32768
#define NE    8192
#define DIM   256
#define EPSF  8.0e-4f
#define LCAP  15

typedef __attribute__((ext_vector_type(8))) short short8;
typedef __attribute__((ext_vector_type(4))) float f32x4;

static __device__ __forceinline__ unsigned pk32(float f) {
  unsigned u = __float_as_uint(f);
  return (u & 0x80000000u) ? ~u : (u | 0x80000000u);
}
static __device__ __forceinline__ float upk32(unsigned p) {
  unsigned u = (p & 0x80000000u) ? (p & 0x7fffffffu) : ~p;
  return __uint_as_float(u);
}
static __device__ __forceinline__ unsigned long long pk64(float s, int idx) {
  return ((unsigned long long)pk32(s) << 32) | (unsigned)idx;
}
static __device__ __forceinline__ unsigned short bf16rne(float f) {
  unsigned u = __float_as_uint(f);
  unsigned r = u + 0x7fffu + ((u >> 16) & 1u);
  return (unsigned short)(r >> 16);
}
static __device__ __forceinline__ void gld16(const void* g, void* l) {
  __builtin_amdgcn_global_load_lds(
      (const __attribute__((address_space(1))) unsigned int*)g,
      (__attribute__((address_space(3))) unsigned int*)l, 16, 0, 0);
}

// ---------------- K1: prep (z2/e2 numpy-pairwise exact, bf16 copies, inits) --
__global__ __launch_bounds__(256) void vq_prep(const float* __restrict__ z,
                                               const float* __restrict__ emb,
                                               float* __restrict__ e2,
                                               float* __restrict__ z2,
                                               unsigned* __restrict__ gmin,
                                               unsigned* __restrict__ list,
                                               unsigned short* __restrict__ zb,
                                               unsigned short* __restrict__ eb,
                                               float* __restrict__ loss_slot) {
  int gid = blockIdx.x * 256 + threadIdx.x;
  if (gid < NTOK) { gmin[gid] = 0xFFFFFFFFu; list[(size_t)gid * 16] = 0u; }
  if (gid == 0) loss_slot[0] = 0.0f;

  int wave = gid >> 6;
  int lane = threadIdx.x & 63;
  int row = wave * 16 + (lane >> 2);            // 0..40959
  int sub = lane & 3;
  int q = sub & 1, h = sub >> 1;

  const float* src = (row < NTOK) ? (z + (size_t)row * DIM)
                                  : (emb + (size_t)(row - NTOK) * DIM);
  unsigned short* dst = (row < NTOK) ? (zb + (size_t)row * DIM)
                                     : (eb + (size_t)(row - NTOK) * DIM);
  const float4* p = reinterpret_cast<const float4*>(src + h * 128 + q * 4);

  float r0, r1, r2, r3, s;
  {
    #pragma clang fp contract(off)
    r0 = 0.0f; r1 = 0.0f; r2 = 0.0f; r3 = 0.0f;
    #pragma unroll
    for (int t = 0; t < 16; t++) {
      float4 v = p[2 * t];
      ushort4 w;
      w.x = bf16rne(v.x); w.y = bf16rne(v.y); w.z = bf16rne(v.z); w.w = bf16rne(v.w);
      *reinterpret_cast<ushort4*>(dst + h * 128 + q * 4 + t * 8) = w;
      float q0 = v.x * v.x, q1 = v.y * v.y, q2 = v.z * v.z, q3 = v.w * v.w;
      r0 = r0 + q0; r1 = r1 + q1; r2 = r2 + q2; r3 = r3 + q3;
    }
    s = (r0 + r1) + (r2 + r3);
    s = s + __shfl_xor(s, 1, 64);
    s = s + __shfl_xor(s, 2, 64);
  }
  if (sub == 0) {
    if (row < NTOK) z2[row] = s;
    else            e2[row - NTOK] = s;
  }
}

// ---------------- K2: bf16 MFMA scoring. collect=0: per-token global min.
//                  collect=1: identical GEMM, emit codes with s <= gmin+eps ---
__global__ __launch_bounds__(256, 2) void vq_mfma(const unsigned short* __restrict__ zb,
                                                  const unsigned short* __restrict__ eb,
                                                  const float* __restrict__ e2,
                                                  unsigned* __restrict__ gmin,
                                                  unsigned* __restrict__ list,
                                                  int collect) {
  __shared__ unsigned short Ab[128 * 32];
  __shared__ unsigned short Bb[128 * 32];
  __shared__ unsigned lmin[128];
  __shared__ float thrS[128];

  const int tid = threadIdx.x;
  const int t0 = blockIdx.x * 128;
  const int e0 = blockIdx.y * 128;
  if (tid < 128) lmin[tid] = 0xFFFFFFFFu;
  const int lane = tid & 63;
  const int wv = tid >> 6;
  const int wm = wv & 1, wn = wv >> 1;

  f32x4 acc[4][4];
  #pragma unroll
  for (int i = 0; i < 4; i++)
    #pragma unroll
    for (int j = 0; j < 4; j++) acc[i][j] = (f32x4)0.0f;

  const size_t gra = (size_t)(t0 + (tid >> 2)) * DIM + (tid & 3) * 8;
  const size_t grb = (size_t)(e0 + (tid >> 2)) * DIM + (tid & 3) * 8;
  char* la0 = (char*)Ab + tid * 16;
  char* lb0 = (char*)Bb + tid * 16;

  const int arix = (wm * 64 + (lane & 15)) * 32 + (lane >> 4) * 8;
  const int brix = (wn * 64 + (lane & 15)) * 32 + (lane >> 4) * 8;

  for (int kc = 0; kc < DIM; kc += 32) {
    __syncthreads();
    gld16(zb + gra + kc, la0);
    gld16(zb + gra + (size_t)64 * DIM + kc, la0 + 4096);
    gld16(eb + grb + kc, lb0);
    gld16(eb + grb + (size_t)64 * DIM + kc, lb0 + 4096);
    __syncthreads();
    short8 a[4], b[4];
    #pragma unroll
    for (int f = 0; f < 4; f++) {
      a[f] = *reinterpret_cast<const short8*>(&Ab[arix + f * 16 * 32]);
      b[f] = *reinterpret_cast<const short8*>(&Bb[brix + f * 16 * 32]);
    }
    #pragma unroll
    for (int fi = 0; fi < 4; fi++)
      #pragma unroll
      for (int fj = 0; fj < 4; fj++)
        acc[fi][fj] = __builtin_amdgcn_mfma_f32_16x16x32_bf16(a[fi], b[fj], acc[fi][fj], 0, 0, 0);
  }

  float e2c[4];
  #pragma unroll
  for (int fj = 0; fj < 4; fj++)
    e2c[fj] = e2[e0 + wn * 64 + fj * 16 + (lane & 15)];

  if (!collect) {
    // pass A: block-local per-token min -> global atomicMin (order-independent)
    #pragma unroll
    for (int fi = 0; fi < 4; fi++) {
      #pragma unroll
      for (int r = 0; r < 4; r++) {
        int tl = wm * 64 + fi * 16 + ((lane >> 4) << 2) + r;
        float mn = 1.0e30f;
        #pragma unroll
        for (int fj = 0; fj < 4; fj++) {
          float s = fmaf(-2.0f, acc[fi][fj][r], e2c[fj]);
          mn = fminf(mn, s);
        }
        atomicMin(&lmin[tl], pk32(mn));
      }
    }
    __syncthreads();
    if (tid < 128) atomicMin(&gmin[t0 + tid], lmin[tid]);
  } else {
    // pass B: deterministic threshold from final gmin; emit candidates
    __syncthreads();
    if (tid < 128) thrS[tid] = upk32(gmin[t0 + tid]) + EPSF;
    __syncthreads();
    #pragma unroll
    for (int fi = 0; fi < 4; fi++) {
      #pragma unroll
      for (int r = 0; r < 4; r++) {
        int tl = wm * 64 + fi * 16 + ((lane >> 4) << 2) + r;
        float th = thrS[tl];
        #pragma unroll
        for (int fj = 0; fj < 4; fj++) {
          float s = fmaf(-2.0f, acc[fi][fj][r], e2c[fj]);
          if (s <= th) {
            unsigned* L = list + (size_t)(t0 + tl) * 16;
            unsigned pos = atomicAdd(L, 1u);
            if (pos < LCAP) L[1 + pos] = (unsigned)(e0 + wn * 64 + fj * 16 + (lane & 15));
          }
        }
      }
    }
  }
}

// ---------------- K3: LDS-staged exact fp32 rescore + outputs ----------------
// esh stride 260 floats: 16B-aligned rows; chain reads hit banks (cc*4+k)%32
// -> worst 2-way aliasing (free). zrow reads are wave-broadcast.
__global__ __launch_bounds__(256) void vq_resolve(const float* __restrict__ z,
                                                  const float* __restrict__ emb,
                                                  const float* __restrict__ z2,
                                                  const float* __restrict__ e2,
                                                  const unsigned* __restrict__ list,
                                                  float* __restrict__ out_zq,
                                                  float* __restrict__ out_loss,
                                                  float* __restrict__ out_idx) {
  __shared__ float zrow[4][256];
  __shared__ float esh[4][LCAP][260];
  __shared__ float lsum[4];
  const int lane = threadIdx.x & 63;
  const int wv = threadIdx.x >> 6;
  const int t = blockIdx.x * 4 + wv;

  const float4 zz = reinterpret_cast<const float4*>(z + (size_t)t * DIM)[lane];
  *reinterpret_cast<float4*>(&zrow[wv][lane * 4]) = zz;

  const unsigned* L = list + (size_t)t * 16;
  unsigned cnt = L[0];
  int winner;

  if (cnt == 1) {
    winner = (int)L[1];
  } else if (cnt <= LCAP) {
    // stage candidate emb rows into LDS with coalesced float4 loads
    for (unsigned cc = 0; cc < cnt; cc++) {
      int c = (int)L[1 + cc];
      float4 ev = reinterpret_cast<const float4*>(emb + (size_t)c * DIM)[lane];
      *reinterpret_cast<float4*>(&esh[wv][cc][lane * 4]) = ev;
    }
    // one lane per candidate: bitwise-np ascending-k fma chain, LDS-only reads
    unsigned long long best = ~0ull;
    if (lane < (int)cnt) {
      int c = (int)L[1 + lane];
      const float* er = &esh[wv][lane][0];
      const float* zr = &zrow[wv][0];
      float m;
      {
        #pragma clang fp contract(off)
        m = 0.0f;
        #pragma unroll 8
        for (int k = 0; k < DIM; k++) m = fmaf(2.0f * zr[k], er[k], m);
        float s = (z2[t] - m) + e2[c];
        best = pk64(s, c);
      }
    }
    #pragma unroll
    for (int off = 32; off > 0; off >>= 1) {
      unsigned long long o = __shfl_xor(best, off, 64);
      best = o < best ? o : best;
    }
    winner = (int)(best & 0xffffffffu);
  } else {
    // overflow (statistically ~never): exact full scan
    const float z2t = z2[t];
    const float* zr = &zrow[wv][0];
    unsigned long long best = ~0ull;
    for (int cb = 0; cb < NE / 64; cb++) {
      int c = cb * 64 + lane;
      const float* er = emb + (size_t)c * DIM;
      float m;
      {
        #pragma clang fp contract(off)
        m = 0.0f;
        #pragma unroll 8
        for (int k = 0; k < DIM; k++) m = fmaf(2.0f * zr[k], er[k], m);
        float s = (z2t - m) + e2[c];
        unsigned long long kk = pk64(s, c);
        best = kk < best ? kk : best;
      }
    }
    #pragma unroll
    for (int off = 32; off > 0; off >>= 1) {
      unsigned long long o = __shfl_xor(best, off, 64);
      best = o < best ? o : best;
    }
    winner = (int)(best & 0xffffffffu);
  }

  const float4 ee = reinterpret_cast<const float4*>(emb + (size_t)winner * DIM)[lane];
  reinterpret_cast<float4*>(out_zq + (size_t)t * DIM)[lane] = ee;
  float dx = ee.x - zz.x, dy = ee.y - zz.y, dz = ee.z - zz.z, dw = ee.w - zz.w;
  float d = dx * dx + dy * dy + dz * dz + dw * dw;
  #pragma unroll
  for (int off = 32; off > 0; off >>= 1) d += __shfl_down(d, off, 64);
  if (lane == 0) {
    lsum[wv] = d;
    out_idx[t] = (float)winner;
  }
  __syncthreads();
  if (threadIdx.x == 0) {
    float tot = (lsum[0] + lsum[1] + lsum[2] + lsum[3]) * (1.25f / 8388608.0f);
    atomicAdd(out_loss, tot);
  }
}

// ====================== round-3 verified fallback path =======================
#define BT 128
#define BE 128
#define BK 32
#define LDW 132

__global__ __launch_bounds__(256) void fb_init(const float* __restrict__ z,
                                               const float* __restrict__ emb,
                                               float* __restrict__ e2,
                                               float* __restrict__ z2,
                                               unsigned long long* __restrict__ k1,
                                               float* __restrict__ loss_slot) {
  int gid = blockIdx.x * 256 + threadIdx.x;
  if (gid < NTOK) k1[gid] = ~0ull;
  if (gid == 0) loss_slot[0] = 0.0f;
  int wave = gid >> 6;
  int lane = threadIdx.x & 63;
  int row = wave * 16 + (lane >> 2);
  int sub = lane & 3;
  int q = sub & 1, h = sub >> 1;
  const float* src = (row < NTOK) ? (z + (size_t)row * DIM)
                                  : (emb + (size_t)(row - NTOK) * DIM);
  const float4* p = reinterpret_cast<const float4*>(src + h * 128 + q * 4);
  float r0, r1, r2, r3, s;
  {
    #pragma clang fp contract(off)
    r0 = 0.0f; r1 = 0.0f; r2 = 0.0f; r3 = 0.0f;
    #pragma unroll
    for (int t = 0; t < 16; t++) {
      float4 v = p[2 * t];
      float q0 = v.x * v.x, q1 = v.y * v.y, q2 = v.z * v.z, q3 = v.w * v.w;
      r0 = r0 + q0; r1 = r1 + q1; r2 = r2 + q2; r3 = r3 + q3;
    }
    s = (r0 + r1) + (r2 + r3);
    s = s + __shfl_xor(s, 1, 64);
    s = s + __shfl_xor(s, 2, 64);
  }
  if (sub == 0) {
    if (row < NTOK) z2[row] = s;
    else            e2[row - NTOK] = s;
  }
}

__global__ __launch_bounds__(256, 4) void fb_score(const float* __restrict__ z,
                                                   const float* __restrict__ emb,
                                                   const float* __restrict__ e2,
                                                   const float* __restrict__ z2,
                                                   unsigned long long* __restrict__ k1) {
  __shared__ float As[BK][LDW];
  __shared__ float Bs[BK][LDW];
  __shared__ unsigned long long mkey[BT];
  const int tid = threadIdx.x;
  const int t0 = blockIdx.x * BT;
  const int e0 = blockIdx.y * BE;
  const int tx = tid & 15;
  const int ty = tid >> 4;
  if (tid < BT) mkey[tid] = ~0ull;
  float acc[8][8];
  #pragma unroll
  for (int i = 0; i < 8; i++)
    #pragma unroll
    for (int j = 0; j < 8; j++) acc[i][j] = 0.0f;
  const float* __restrict__ zt = z + (size_t)t0 * DIM;
  const float* __restrict__ et = emb + (size_t)e0 * DIM;
  for (int kc = 0; kc < DIM; kc += BK) {
    __syncthreads();
    #pragma unroll
    for (int i = 0; i < 4; i++) {
      int f = tid + i * 256;
      int row = f >> 3;
      int kq = f & 7;
      const float4 va = *reinterpret_cast<const float4*>(zt + row * DIM + kc + kq * 4);
      const float4 vb = *reinterpret_cast<const float4*>(et + row * DIM + kc + kq * 4);
      int k = kq * 4;
      As[k + 0][row] = va.x * 2.0f; As[k + 1][row] = va.y * 2.0f;
      As[k + 2][row] = va.z * 2.0f; As[k + 3][row] = va.w * 2.0f;
      Bs[k + 0][row] = vb.x; Bs[k + 1][row] = vb.y;
      Bs[k + 2][row] = vb.z; Bs[k + 3][row] = vb.w;
    }
    __syncthreads();
    #pragma unroll 4
    for (int k = 0; k < BK; k++) {
      float a[8], b[8];
      *(float4*)&a[0] = *(const float4*)&As[k][ty * 8];
      *(float4*)&a[4] = *(const float4*)&As[k][ty * 8 + 4];
      *(float4*)&b[0] = *(const float4*)&Bs[k][tx * 8];
      *(float4*)&b[4] = *(const float4*)&Bs[k][tx * 8 + 4];
      #pragma unroll
      for (int i = 0; i < 8; i++)
        #pragma unroll
        for (int j = 0; j < 8; j++)
          acc[i][j] = fmaf(a[i], b[j], acc[i][j]);
    }
  }
  float e2c[8], z2t[8];
  *(float4*)&e2c[0] = *(const float4*)(e2 + e0 + tx * 8);
  *(float4*)&e2c[4] = *(const float4*)(e2 + e0 + tx * 8 + 4);
  *(float4*)&z2t[0] = *(const float4*)(z2 + t0 + ty * 8);
  *(float4*)&z2t[4] = *(const float4*)(z2 + t0 + ty * 8 + 4);
  {
    #pragma clang fp contract(off)
    #pragma unroll
    for (int i = 0; i < 8; i++) {
      int trow = ty * 8 + i;
      unsigned long long best = ~0ull;
      #pragma unroll
      for (int j = 0; j < 8; j++) {
        float t1 = z2t[i] - acc[i][j];
        float s = t1 + e2c[j];
        unsigned long long kk = pk64(s, e0 + tx * 8 + j);
        best = kk < best ? kk : best;
      }
      atomicMin(&mkey[trow], best);
    }
  }
  __syncthreads();
  if (tid < BT) atomicMin(&k1[t0 + tid], mkey[tid]);
}

__global__ __launch_bounds__(256) void fb_out(const float* __restrict__ z,
                                              const float* __restrict__ emb,
                                              const unsigned long long* __restrict__ k1,
                                              float* __restrict__ out_zq,
                                              float* __restrict__ out_loss,
                                              float* __restrict__ out_idx) {
  __shared__ float lsum[4];
  const int wid = threadIdx.x >> 6;
  const int lane = threadIdx.x & 63;
  const int tbase = blockIdx.x * 16 + wid * 4;
  float s_acc = 0.0f;
  #pragma unroll
  for (int it = 0; it < 4; it++) {
    int t = tbase + it;
    unsigned idx = (unsigned)(k1[t] & 0xffffffffu);
    float4 e = reinterpret_cast<const float4*>(emb + (size_t)idx * DIM)[lane];
    float4 zz = reinterpret_cast<const float4*>(z + (size_t)t * DIM)[lane];
    reinterpret_cast<float4*>(out_zq + (size_t)t * DIM)[lane] = e;
    float dx = e.x - zz.x, dy = e.y - zz.y, dz = e.z - zz.z, dw = e.w - zz.w;
    s_acc += dx * dx + dy * dy + dz * dz + dw * dw;
    if (lane == 0) out_idx[t] = (float)idx;
  }
  #pragma unroll
  for (int off = 32; off > 0; off >>= 1) s_acc += __shfl_down(s_acc, off, 64);
  if (lane == 0) lsum[wid] = s_acc;
  __syncthreads();
  if (threadIdx.x == 0) {
    float tot = (lsum[0] + lsum[1] + lsum[2] + lsum[3]) * (1.25f / 8388608.0f);
    atomicAdd(out_loss, tot);
  }
}

// ============================== launcher =====================================
extern "C" void kernel_launch(void* const* d_in, const int* in_sizes, int n_in,
                              void* d_out, int out_size, void* d_ws, size_t ws_size,
                              hipStream_t stream) {
  const float* z = (const float*)d_in[0];
  const float* emb = (const float*)d_in[1];
  float* out = (float*)d_out;
  float* out_zq = out;
  float* out_loss = out + (size_t)NTOK * DIM;
  float* out_idx = out_loss + 1;

  // ws offsets (fast path): e2 | z2 | gmin | list | zb | eb
  const size_t OFF_Z2   = 32768;
  const size_t OFF_GMIN = 163840;
  const size_t OFF_LIST = 294912;
  const size_t OFF_ZB   = 2392064;
  const size_t OFF_EB   = 19169280;
  const size_t REQ      = 23363584;

  if (ws_size >= REQ) {
    float* e2 = (float*)d_ws;
    float* z2 = (float*)((char*)d_ws + OFF_Z2);
    unsigned* gmin = (unsigned*)((char*)d_ws + OFF_GMIN);
    unsigned* list = (unsigned*)((char*)d_ws + OFF_LIST);
    unsigned short* zb = (unsigned short*)((char*)d_ws + OFF_ZB);
    unsigned short* eb = (unsigned short*)((char*)d_ws + OFF_EB);

    hipLaunchKernelGGL(vq_prep, dim3(640), dim3(256), 0, stream,
                       z, emb, e2, z2, gmin, list, zb, eb, out_loss);
    hipLaunchKernelGGL(vq_mfma, dim3(NTOK / 128, NE / 128), dim3(256), 0, stream,
                       zb, eb, e2, gmin, list, 0);
    hipLaunchKernelGGL(vq_mfma, dim3(NTOK / 128, NE / 128), dim3(256), 0, stream,
                       zb, eb, e2, gmin, list, 1);
    hipLaunchKernelGGL(vq_resolve, dim3(NTOK / 4), dim3(256), 0, stream,
                       z, emb, z2, e2, list, out_zq, out_loss, out_idx);
  } else {
    float* e2 = (float*)d_ws;
    float* z2 = (float*)((char*)d_ws + 32768);
    unsigned long long* k1 = (unsigned long long*)((char*)d_ws + 262144);
    hipLaunchKernelGGL(fb_init, dim3(640), dim3(256), 0, stream,
                       z, emb, e2, z2, k1, out_loss);
    hipLaunchKernelGGL(fb_score, dim3(NTOK / BT, NE / BE), dim3(256), 0, stream,
                       z, emb, e2, z2, k1);
    hipLaunchKernelGGL(fb_out, dim3(NTOK / 16), dim3(256), 0, stream,
                       z, emb, k1, out_zq, out_loss, out_idx);
  }
}